// Round 9
// baseline (989.425 us; speedup 1.0000x reference)
//
#include <hip/hip_runtime.h>

#define SEQ   4096
#define HID   4096
#define EDIM  1024
#define NHEAD 4

typedef __attribute__((ext_vector_type(8))) short short8;
typedef __attribute__((ext_vector_type(16))) float f32x16;

typedef const __attribute__((address_space(1))) void* gas_ptr;
typedef __attribute__((address_space(3))) void* las_ptr;
#define GLD16(g, l) __builtin_amdgcn_global_load_lds((gas_ptr)(g), (las_ptr)(l), 16, 0, 0)

#define BARRIER() __builtin_amdgcn_s_barrier()
#define SCHED0()  __builtin_amdgcn_sched_barrier(0)
#define VMC0()    asm volatile("s_waitcnt vmcnt(0)" ::: "memory")

__device__ __forceinline__ unsigned short f2bf(float f) {
  union { float f; unsigned u; } v; v.f = f;
  unsigned r = v.u + 0x7fffu + ((v.u >> 16) & 1u);  // RNE
  return (unsigned short)(r >> 16);
}
__device__ __forceinline__ float bf2f(unsigned short u) {
  union { unsigned u; float f; } v; v.u = ((unsigned)u) << 16;
  return v.f;
}

// ---------------- h: f32 -> bf16 ----------------
__global__ __launch_bounds__(256) void hconv_kernel(const float* __restrict__ in,
                                                    unsigned short* __restrict__ out) {
  size_t i = ((size_t)blockIdx.x * 256 + threadIdx.x) * 8;
  const float4 a = *(const float4*)(in + i);
  const float4 b = *(const float4*)(in + i + 4);
  short8 o;
  o[0] = (short)f2bf(a.x); o[1] = (short)f2bf(a.y);
  o[2] = (short)f2bf(a.z); o[3] = (short)f2bf(a.w);
  o[4] = (short)f2bf(b.x); o[5] = (short)f2bf(b.y);
  o[6] = (short)f2bf(b.z); o[7] = (short)f2bf(b.w);
  *(short8*)(out + i) = o;
}

// ---------------- W [mat][head][D][E] f32 -> Wt [mat*4+head][E][D] bf16 ----------------
__global__ __launch_bounds__(256) void wconv_kernel(const float* __restrict__ Wq,
                                                    const float* __restrict__ Wk,
                                                    const float* __restrict__ Wv,
                                                    unsigned short* __restrict__ wt) {
  const int mh = blockIdx.y;               // 0..11
  const int mat = mh >> 2, head = mh & 3;
  const float* W = (mat == 0 ? Wq : (mat == 1 ? Wk : Wv)) + (size_t)head * HID * EDIM; // [D][E]
  unsigned short* out = wt + (size_t)mh * EDIM * HID;                                  // [E][D]
  const int tile = blockIdx.x;             // (D/64)*(E/64) = 64*16
  const int td = tile >> 4;                // d-tile 0..63
  const int te = tile & 15;                // e-tile 0..15
  __shared__ float lds[64][65];
  const int tid = threadIdx.x;
  const int r = tid >> 4, c4 = (tid & 15) * 4;
#pragma unroll
  for (int it = 0; it < 4; ++it) {
    int dr = r + 16 * it;
    const float4 v = *(const float4*)&W[(size_t)(td * 64 + dr) * EDIM + te * 64 + c4];
    lds[dr][c4 + 0] = v.x; lds[dr][c4 + 1] = v.y;
    lds[dr][c4 + 2] = v.z; lds[dr][c4 + 3] = v.w;
  }
  __syncthreads();
#pragma unroll
  for (int it = 0; it < 4; ++it) {
    int er = r + 16 * it;
    ushort4 o;
    o.x = f2bf(lds[c4 + 0][er]); o.y = f2bf(lds[c4 + 1][er]);
    o.z = f2bf(lds[c4 + 2][er]); o.w = f2bf(lds[c4 + 3][er]);
    *(ushort4*)&out[(size_t)(te * 64 + er) * HID + td * 64 + c4] = o;
  }
}

// ---------------- 256x256 slice-pipelined bf16 MFMA GEMM (32x32x16) ----------------
// r8 core (best-so-far, ~860 TF): BK=64, 8 waves (2Mx4N), 128x64/wave (acc f32x16[4][2]).
// Ring-2 LDS, one-slice-ahead fragment pipeline, 2 barriers + 1 vmcnt(0) per K-tile.
// Swizzle f(row)=(row^(row>>3))&7 on 16B slots, 0 bank conflicts (r5-verified).
// MODE 0: merged Q/K/V projections. z in [0,12): mat=z>>2, head=z&3. A shared (hB).
//         mat 0/1 -> row-major bf16 out + bias; mat 2 -> transposed V^T out + bias.
// MODE 2: scores. Writes exp(acc*scale) bf16 (fused softmax numerator; no max-sub
//         needed: |s|<~8) and atomically accumulates per-row sums (if rowsum != null;
//         else legacy raw-score path for the fallback softmax kernel).
// MODE 3: PV. f32 out to out[s][head*E+e], divided by rowsum (if non-null).
template <int MODE>
__global__ __launch_bounds__(512, 2) void gemm256_kernel(
    const unsigned short* __restrict__ Aall, const unsigned short* __restrict__ Ball,
    long long aBatch, long long bBatch, int K,
    const float* __restrict__ b0, const float* __restrict__ b1,
    const float* __restrict__ b2,
    void* __restrict__ o0, void* __restrict__ o1, void* __restrict__ o2,
    float* __restrict__ rowsum, float scale, int gx, int gxy) {
  extern __shared__ char smem[];

  // XCD-aware bijective block swizzle (all grids have nwg % 8 == 0)
  const int nwg = (int)gridDim.x;
  const int lin = (int)blockIdx.x;
  int wg = (lin & 7) * (nwg >> 3) + (lin >> 3);
  const int z = wg / gxy; wg -= z * gxy;
  const int by = wg / gx;
  const int bx = wg - by * gx;
  const int bm = by * 256, bn = bx * 256;

  const unsigned short* A = Aall + (size_t)z * aBatch;
  const unsigned short* B = Ball + (size_t)z * bBatch;

  const int tid = threadIdx.x;           // 0..511
  const int lane = tid & 63, wid = tid >> 6;
  const int wr = wid >> 2, wc = wid & 3; // wave -> (2 x 4) output grid
  const int la31 = lane & 31, lg2 = lane >> 5;

  // ---- staging: per region 128 rows x 128 B; thread covers rows srow+{0,64,...}
  const int srow = tid >> 3;                                // 0..63
  const int sk = ((tid & 7) ^ ((srow ^ (srow >> 3)) & 7)) * 8;
  const unsigned short* aS0 = A + (size_t)(bm +   0 + srow) * K + sk;
  const unsigned short* aS1 = A + (size_t)(bm +  64 + srow) * K + sk;
  const unsigned short* aS2 = A + (size_t)(bm + 128 + srow) * K + sk;
  const unsigned short* aS3 = A + (size_t)(bm + 192 + srow) * K + sk;
  const unsigned short* bS0 = B + (size_t)(bn +   0 + srow) * K + sk;
  const unsigned short* bS1 = B + (size_t)(bn +  64 + srow) * K + sk;
  const unsigned short* bS2 = B + (size_t)(bn + 128 + srow) * K + sk;
  const unsigned short* bS3 = B + (size_t)(bn + 192 + srow) * K + sk;

#define STG(tt)                                                           \
  do {                                                                    \
    char* _d = smem + (((tt) & 1) << 16) + tid * 16;                      \
    GLD16(aS0 + (size_t)(tt) * 64, _d);                                   \
    GLD16(aS1 + (size_t)(tt) * 64, _d + 8192);                            \
    GLD16(aS2 + (size_t)(tt) * 64, _d + 16384);                          \
    GLD16(aS3 + (size_t)(tt) * 64, _d + 24576);                          \
    GLD16(bS0 + (size_t)(tt) * 64, _d + 32768);                          \
    GLD16(bS1 + (size_t)(tt) * 64, _d + 40960);                          \
    GLD16(bS2 + (size_t)(tt) * 64, _d + 49152);                          \
    GLD16(bS3 + (size_t)(tt) * 64, _d + 57344);                          \
  } while (0)

  // ---- fragment read bases (row stride 128 B, XOR-swizzled 16B slots)
  int aO[4], aX[4];
#pragma unroll
  for (int m = 0; m < 4; ++m) {
    const int arow = wr * 128 + m * 32 + la31;
    aO[m] = arow * 128;
    aX[m] = (arow ^ (arow >> 3)) & 7;
  }
  int bO[2], bX[2];
#pragma unroll
  for (int n = 0; n < 2; ++n) {
    const int brow = wc * 64 + n * 32 + la31;
    bO[n] = 32768 + brow * 128;
    bX[n] = (brow ^ (brow >> 3)) & 7;
  }

#define RD_A(SET, BASE, KS)                                               \
  _Pragma("unroll") for (int m = 0; m < 4; ++m)                           \
    SET[m] = *(const short8*)((BASE) + aO[m] +                            \
                              (((((KS) << 1) + lg2) ^ aX[m]) << 4));
#define RD_B(SET, BASE, KS)                                               \
  _Pragma("unroll") for (int n = 0; n < 2; ++n)                           \
    SET[n] = *(const short8*)((BASE) + bO[n] +                            \
                              (((((KS) << 1) + lg2) ^ bX[n]) << 4));
#define MFMA_S(AV, BV)                                                    \
  __builtin_amdgcn_s_setprio(1);                                          \
  _Pragma("unroll") for (int m = 0; m < 4; ++m)                           \
  _Pragma("unroll") for (int n = 0; n < 2; ++n)                           \
    acc[m][n] = __builtin_amdgcn_mfma_f32_32x32x16_bf16(                  \
        AV[m], BV[n], acc[m][n], 0, 0, 0);                                \
  __builtin_amdgcn_s_setprio(0);

  f32x16 acc[4][2];
#pragma unroll
  for (int m = 0; m < 4; ++m)
#pragma unroll
    for (int n = 0; n < 2; ++n)
#pragma unroll
      for (int r = 0; r < 16; ++r) acc[m][n][r] = 0.f;

  const int NT = K >> 6;    // K-tiles of 64

  short8 avA[4], bvA[2], avB[4], bvB[2];

  // ---- prologue: stage tile 0; wait; read slice0 into set A
  STG(0);
  VMC0();
  BARRIER();
  RD_A(avA, smem, 0); RD_B(bvA, smem, 0);
  SCHED0();

  for (int t = 0; t < NT; ++t) {
    const char* base  = smem + ((t & 1) << 16);
    const char* nbase = smem + (((t + 1) & 1) << 16);

    // ph0: stage t+1 -> slot(t-1) [dead]; read slice1; MFMA slice0
    if (t + 1 < NT) STG(t + 1);
    RD_A(avB, base, 1); RD_B(bvB, base, 1);
    SCHED0();
    MFMA_S(avA, bvA);
    SCHED0();

    // ph1: read slice2; MFMA slice1
    RD_A(avA, base, 2); RD_B(bvA, base, 2);
    SCHED0();
    MFMA_S(avB, bvB);
    SCHED0();

    // ph2: read slice3; MFMA slice2
    RD_A(avB, base, 3); RD_B(bvB, base, 3);
    SCHED0();
    MFMA_S(avA, bvA);
    SCHED0();

    // ph3: prove STG(t+1) landed; read next tile slice0; MFMA slice3
    VMC0();
    BARRIER();
    if (t + 1 < NT) { RD_A(avA, nbase, 0); RD_B(bvA, nbase, 0); }
    SCHED0();
    MFMA_S(avB, bvB);
    SCHED0();
    BARRIER();
  }
#undef STG
#undef RD_A
#undef RD_B
#undef MFMA_S

  // ---- epilogue (C/D: col = lane&31, row = (r&3) + 8*(r>>2) + 4*(lane>>5))
  const long long QKB = (long long)SEQ * EDIM;
  const long long SSB = (long long)SEQ * SEQ;
  float bvv[2];
  if (MODE == 0) {
    const int mat = z >> 2, head = z & 3;
    const float* bias = (mat == 0 ? b0 : mat == 1 ? b1 : b2) + head * EDIM;
#pragma unroll
    for (int n = 0; n < 2; ++n) bvv[n] = bias[bn + wc * 64 + n * 32 + la31];
  }
#pragma unroll
  for (int m = 0; m < 4; ++m)
#pragma unroll
    for (int r = 0; r < 16; ++r) {
      const int grow = bm + wr * 128 + m * 32 + (r & 3) + 8 * (r >> 2) + 4 * lg2;
      const int col0 = bn + wc * 64 + la31;         // n=0 column; n=1 is col0+32
      float v0 = acc[m][0][r], v1 = acc[m][1][r];
      if (MODE == 0) {
        v0 += bvv[0]; v1 += bvv[1];
        const int mat = z >> 2, head = z & 3;
        if (mat == 2) {  // V^T [e][s]
          unsigned short* o = (unsigned short*)o2 + (size_t)head * QKB;
          o[(size_t)col0 * SEQ + grow]        = f2bf(v0);
          o[(size_t)(col0 + 32) * SEQ + grow] = f2bf(v1);
        } else {
          unsigned short* o =
              (unsigned short*)(mat == 0 ? o0 : o1) + (size_t)head * QKB;
          o[(size_t)grow * EDIM + col0]      = f2bf(v0);
          o[(size_t)grow * EDIM + col0 + 32] = f2bf(v1);
        }
      } else if (MODE == 2) {
        unsigned short* o = (unsigned short*)o0 + (size_t)z * SSB;
        if (rowsum) {
          const float e0 = __expf(v0 * scale), e1 = __expf(v1 * scale);
          o[(size_t)grow * SEQ + col0]      = f2bf(e0);
          o[(size_t)grow * SEQ + col0 + 32] = f2bf(e1);
          float rp = e0 + e1;          // row-partial over this lane's 2 cols
          rp += __shfl_xor(rp, 1);  rp += __shfl_xor(rp, 2);
          rp += __shfl_xor(rp, 4);  rp += __shfl_xor(rp, 8);
          rp += __shfl_xor(rp, 16);    // sum over la31 (stays within 32-halves)
          if (la31 == 0) atomicAdd(&rowsum[(size_t)z * SEQ + grow], rp);
        } else {                       // legacy raw-score path
          o[(size_t)grow * SEQ + col0]      = f2bf(v0 * scale);
          o[(size_t)grow * SEQ + col0 + 32] = f2bf(v1 * scale);
        }
      } else {  // MODE 3: PV -> final f32 out[s][head*E + e]
        float rinv = 1.0f;
        if (rowsum) rinv = 1.0f / rowsum[(size_t)z * SEQ + grow];
        float* o = (float*)o0 + (size_t)z * EDIM;
        o[(size_t)grow * (NHEAD * EDIM) + col0]      = v0 * rinv;
        o[(size_t)grow * (NHEAD * EDIM) + col0 + 32] = v1 * rinv;
      }
    }
}

// ---------------- fallback row softmax, in place on bf16 [nrows][SEQ] ----------------
__global__ __launch_bounds__(256) void softmax_kernel(unsigned short* __restrict__ Sb) {
  const size_t row = blockIdx.x;
  unsigned short* p = Sb + row * (size_t)SEQ;
  const int tid = threadIdx.x;
  const int lane = tid & 63, wid = tid >> 6;
  float v[16];
  const short8 u0 = *(const short8*)&p[tid * 16];
  const short8 u1 = *(const short8*)&p[tid * 16 + 8];
#pragma unroll
  for (int j = 0; j < 8; ++j) v[j] = bf2f((unsigned short)u0[j]);
#pragma unroll
  for (int j = 0; j < 8; ++j) v[8 + j] = bf2f((unsigned short)u1[j]);
  float mx = v[0];
#pragma unroll
  for (int j = 1; j < 16; ++j) mx = fmaxf(mx, v[j]);
#pragma unroll
  for (int off = 32; off; off >>= 1) mx = fmaxf(mx, __shfl_xor(mx, off));
  __shared__ float red[8];
  if (lane == 0) red[wid] = mx;
  __syncthreads();
  mx = fmaxf(fmaxf(red[0], red[1]), fmaxf(red[2], red[3]));
  float s = 0.f;
#pragma unroll
  for (int j = 0; j < 16; ++j) { v[j] = __expf(v[j] - mx); s += v[j]; }
#pragma unroll
  for (int off = 32; off; off >>= 1) s += __shfl_xor(s, off);
  if (lane == 0) red[4 + wid] = s;
  __syncthreads();
  s = (red[4] + red[5]) + (red[6] + red[7]);
  const float inv = 1.0f / s;
  short8 o0, o1;
#pragma unroll
  for (int j = 0; j < 8; ++j) o0[j] = (short)f2bf(v[j] * inv);
#pragma unroll
  for (int j = 0; j < 8; ++j) o1[j] = (short)f2bf(v[8 + j] * inv);
  *(short8*)&p[tid * 16] = o0;
  *(short8*)&p[tid * 16 + 8] = o1;
}

extern "C" void kernel_launch(void* const* d_in, const int* in_sizes, int n_in,
                              void* d_out, int out_size, void* d_ws, size_t ws_size,
                              hipStream_t stream) {
  const float* h  = (const float*)d_in[0];
  const float* Wq = (const float*)d_in[1];
  const float* bq = (const float*)d_in[2];
  const float* Wk = (const float*)d_in[3];
  const float* bk = (const float*)d_in[4];
  const float* Wv = (const float*)d_in[5];
  const float* bv = (const float*)d_in[6];
  float* out = (float*)d_out;
  char* ws = (char*)d_ws;

  (void)hipFuncSetAttribute((const void*)&gemm256_kernel<0>,
                            hipFuncAttributeMaxDynamicSharedMemorySize, 131072);
  (void)hipFuncSetAttribute((const void*)&gemm256_kernel<2>,
                            hipFuncAttributeMaxDynamicSharedMemorySize, 131072);
  (void)hipFuncSetAttribute((const void*)&gemm256_kernel<3>,
                            hipFuncAttributeMaxDynamicSharedMemorySize, 131072);

  // ws layout (224 MB + 64 KB):
  //  [0,32MB)    h_bf16 [S][HID]          -- dead after projections
  //  [32,128MB)  Wt bf16 [12][E][HID]     -- dead after projections
  //  [0,128MB)   Sb bf16 [H][S][S]        -- exp-scores (reuses the two above)
  //  [128,160)   Qb bf16 [H][S][E]
  //  [160,192)   Kb bf16 [H][S][E]
  //  [192,224)   Vt bf16 [H][E][S]
  //  [224MB, +64KB) rowsum f32 [H][S]     -- fused-softmax denominators
  unsigned short* hB = (unsigned short*)ws;
  unsigned short* wt = (unsigned short*)(ws + (32ull << 20));
  unsigned short* Sb = (unsigned short*)ws;
  unsigned short* Qb = (unsigned short*)(ws + (128ull << 20));
  unsigned short* Kb = (unsigned short*)(ws + (160ull << 20));
  unsigned short* Vt = (unsigned short*)(ws + (192ull << 20));
  float* rowsum = (float*)(ws + (224ull << 20));
  const bool fused = ws_size >= (224ull << 20) + (size_t)NHEAD * SEQ * sizeof(float);

  const long long WED = (long long)EDIM * HID;   // per-(mat,head) Wt elems
  const long long QKB = (long long)SEQ * EDIM;   // per-head Q/K/V elems
  const long long SSB = (long long)SEQ * SEQ;    // per-head score elems

  hconv_kernel<<<dim3((SEQ * (size_t)HID) / (256 * 8)), 256, 0, stream>>>(h, hB);
  wconv_kernel<<<dim3((HID / 64) * (EDIM / 64), 12), 256, 0, stream>>>(Wq, Wk, Wv, wt);
  if (fused)
    hipMemsetAsync(rowsum, 0, (size_t)NHEAD * SEQ * sizeof(float), stream);

  // Merged projections: z in [0,12) = (mat,head); grid 4 x 16 x 12 = 768 blocks
  gemm256_kernel<0><<<dim3(768), 512, 131072, stream>>>(
      hB, wt, 0, WED, HID, bq, bk, bv, Qb, Kb, Vt, nullptr, 1.f, 4, 64);

  // Scores + exp + rowsum: M=N=S, K=E -> 16 x 16 x 4 = 1024 blocks
  gemm256_kernel<2><<<dim3(1024), 512, 131072, stream>>>(
      Qb, Kb, QKB, QKB, EDIM, nullptr, nullptr, nullptr, Sb, nullptr, nullptr,
      fused ? rowsum : nullptr, 0.03125f, 16, 256);

  if (!fused)
    softmax_kernel<<<dim3(NHEAD * SEQ), 256, 0, stream>>>(Sb);

  // PV (+ divide by rowsum): M=S, N=E, K=S -> 4 x 16 x 4 = 256 blocks
  gemm256_kernel<3><<<dim3(256), 512, 131072, stream>>>(
      Sb, Vt, SSB, QKB, SEQ, nullptr, nullptr, nullptr, out, nullptr, nullptr,
      fused ? rowsum : nullptr, 1.f, 4, 64);
}

// Round 10
// 898.390 us; speedup vs baseline: 1.1013x; 1.1013x over previous
//
#include <hip/hip_runtime.h>

#define SEQ   4096
#define HID   4096
#define EDIM  1024
#define NHEAD 4

typedef __attribute__((ext_vector_type(8))) short short8;
typedef __attribute__((ext_vector_type(16))) float f32x16;

typedef const __attribute__((address_space(1))) void* gas_ptr;
typedef __attribute__((address_space(3))) void* las_ptr;
#define GLD16(g, l) __builtin_amdgcn_global_load_lds((gas_ptr)(g), (las_ptr)(l), 16, 0, 0)

#define BARRIER() __builtin_amdgcn_s_barrier()
#define SCHED0()  __builtin_amdgcn_sched_barrier(0)
#define LGKM0()   asm volatile("s_waitcnt lgkmcnt(0)" ::: "memory")
#define VMC0()    asm volatile("s_waitcnt vmcnt(0)" ::: "memory")

__device__ __forceinline__ unsigned short f2bf(float f) {
  union { float f; unsigned u; } v; v.f = f;
  unsigned r = v.u + 0x7fffu + ((v.u >> 16) & 1u);  // RNE
  return (unsigned short)(r >> 16);
}
__device__ __forceinline__ float bf2f(unsigned short u) {
  union { unsigned u; float f; } v; v.u = ((unsigned)u) << 16;
  return v.f;
}

// ---------------- h: f32 -> bf16 ----------------
__global__ __launch_bounds__(256) void hconv_kernel(const float* __restrict__ in,
                                                    unsigned short* __restrict__ out) {
  size_t i = ((size_t)blockIdx.x * 256 + threadIdx.x) * 8;
  const float4 a = *(const float4*)(in + i);
  const float4 b = *(const float4*)(in + i + 4);
  short8 o;
  o[0] = (short)f2bf(a.x); o[1] = (short)f2bf(a.y);
  o[2] = (short)f2bf(a.z); o[3] = (short)f2bf(a.w);
  o[4] = (short)f2bf(b.x); o[5] = (short)f2bf(b.y);
  o[6] = (short)f2bf(b.z); o[7] = (short)f2bf(b.w);
  *(short8*)(out + i) = o;
}

// ---------------- W [mat][head][D][E] f32 -> Wt [mat*4+head][E][D] bf16 ----------------
__global__ __launch_bounds__(256) void wconv_kernel(const float* __restrict__ Wq,
                                                    const float* __restrict__ Wk,
                                                    const float* __restrict__ Wv,
                                                    unsigned short* __restrict__ wt) {
  const int mh = blockIdx.y;               // 0..11
  const int mat = mh >> 2, head = mh & 3;
  const float* W = (mat == 0 ? Wq : (mat == 1 ? Wk : Wv)) + (size_t)head * HID * EDIM; // [D][E]
  unsigned short* out = wt + (size_t)mh * EDIM * HID;                                  // [E][D]
  const int tile = blockIdx.x;             // (D/64)*(E/64) = 64*16
  const int td = tile >> 4;                // d-tile 0..63
  const int te = tile & 15;                // e-tile 0..15
  __shared__ float lds[64][65];
  const int tid = threadIdx.x;
  const int r = tid >> 4, c4 = (tid & 15) * 4;
#pragma unroll
  for (int it = 0; it < 4; ++it) {
    int dr = r + 16 * it;
    const float4 v = *(const float4*)&W[(size_t)(td * 64 + dr) * EDIM + te * 64 + c4];
    lds[dr][c4 + 0] = v.x; lds[dr][c4 + 1] = v.y;
    lds[dr][c4 + 2] = v.z; lds[dr][c4 + 3] = v.w;
  }
  __syncthreads();
#pragma unroll
  for (int it = 0; it < 4; ++it) {
    int er = r + 16 * it;
    ushort4 o;
    o.x = f2bf(lds[c4 + 0][er]); o.y = f2bf(lds[c4 + 1][er]);
    o.z = f2bf(lds[c4 + 2][er]); o.w = f2bf(lds[c4 + 3][er]);
    *(ushort4*)&out[(size_t)(te * 64 + er) * HID + td * 64 + c4] = o;
  }
}

// ---------------- 256x256 bf16 MFMA GEMM (32x32x16), 16 waves / high occupancy ----------
// C = A * Bt^T. A [M][K] row-major, Bt [N][K] row-major. BK=64. 1024 threads = 16 waves
// (4M x 4N), wave tile 64x64 = 2x2 tiles of 32x32 -> acc f32x16[2][2] = 64 regs, total
// ~120 <= 128 -> __launch_bounds__(1024,4) = 4 waves/SIMD = 16 waves/CU (2x prior TLP).
// Ring-2 LDS 128KB. One VMC0 + one BARRIER per K-tile (r6 discipline): at tile top,
// own STG(t) (issued last tile, ~1 tile flight > HBM latency) drained; barrier proves
// everyone's STG(t) landed AND everyone finished reading slot t^1 -> STG(t+1) safe.
// Swizzle (r5-verified, 0 conflicts): phys 16B-slot = logical ^ f(row),
// f(row)=(row^(row>>3))&7; staging source pre-permuted (f(row+128)=f(row)).
// Frag maps: A/B lane l: row/col = l&31, k = (l>>5)*8 + j.
// C/D (verified m74/m101): col = lane&31, row = (r&3) + 8*(r>>2) + 4*(lane>>5).
// MODE 0: bf16 out [row][col], +bias[col]
// MODE 1: bf16 out [col][row], +bias[col]   (transposed write, for V^T)
// MODE 2: bf16 out [row][col], *scale       (scores)
// MODE 3: f32  out [row][col]               (final output)
template <int MODE>
__global__ __launch_bounds__(1024, 4) void gemm1024_kernel(
    const unsigned short* __restrict__ Aall, const unsigned short* __restrict__ Ball,
    long long aBatch, long long bBatch, int K,
    const float* __restrict__ biasAll, long long biasBatch,
    void* __restrict__ outAll, long long outBatch, int ldOut, float scale,
    int gx, int gxy) {
  extern __shared__ char smem[];

  // XCD-aware bijective block swizzle (all grids have nwg % 8 == 0)
  const int nwg = (int)gridDim.x;
  const int lin = (int)blockIdx.x;
  int wg = (lin & 7) * (nwg >> 3) + (lin >> 3);
  const int z = wg / gxy; wg -= z * gxy;
  const int by = wg / gx;
  const int bx = wg - by * gx;
  const int bm = by * 256, bn = bx * 256;

  const unsigned short* A = Aall + (size_t)z * aBatch;
  const unsigned short* B = Ball + (size_t)z * bBatch;

  const int tid = threadIdx.x;           // 0..1023
  const int lane = tid & 63, wid = tid >> 6;   // 16 waves
  const int wr = wid >> 2, wc = wid & 3;       // 4 x 4 wave grid
  const int la31 = lane & 31, lg2 = lane >> 5;

  // ---- staging: A region 256 rows x 128B (32KB); thread covers rows tid>>3, +128.
  const int srow = tid >> 3;                                // 0..127
  const int sk = ((tid & 7) ^ ((srow ^ (srow >> 3)) & 7)) * 8;
  const unsigned short* aS0 = A + (size_t)(bm + srow) * K + sk;
  const unsigned short* aS1 = aS0 + (size_t)128 * K;
  const unsigned short* bS0 = B + (size_t)(bn + srow) * K + sk;
  const unsigned short* bS1 = bS0 + (size_t)128 * K;

// per tile: 4 GLD16/thread (A 32KB @0, B 32KB @32768 within 64KB slot)
#define STG(tt)                                                           \
  do {                                                                    \
    char* _d = smem + (((tt) & 1) << 16) + tid * 16;                      \
    GLD16(aS0 + (size_t)(tt) * 64, _d);                                   \
    GLD16(aS1 + (size_t)(tt) * 64, _d + 16384);                          \
    GLD16(bS0 + (size_t)(tt) * 64, _d + 32768);                          \
    GLD16(bS1 + (size_t)(tt) * 64, _d + 49152);                          \
  } while (0)

  // ---- fragment read bases (row stride 128B, XOR-swizzled 16B slots)
  int aO[2], aX[2];
#pragma unroll
  for (int m = 0; m < 2; ++m) {
    const int arow = wr * 64 + m * 32 + la31;
    aO[m] = arow * 128;
    aX[m] = (arow ^ (arow >> 3)) & 7;
  }
  int bO[2], bX[2];
#pragma unroll
  for (int n = 0; n < 2; ++n) {
    const int brow = wc * 64 + n * 32 + la31;
    bO[n] = 32768 + brow * 128;
    bX[n] = (brow ^ (brow >> 3)) & 7;
  }

#define RD2(S0, S1)                                                       \
  _Pragma("unroll") for (int m = 0; m < 2; ++m) {                         \
    av[m][0] = *(const short8*)(base + aO[m] +                            \
                                (((((S0) << 1) + lg2) ^ aX[m]) << 4));    \
    av[m][1] = *(const short8*)(base + aO[m] +                            \
                                (((((S1) << 1) + lg2) ^ aX[m]) << 4));    \
  }                                                                       \
  _Pragma("unroll") for (int n = 0; n < 2; ++n) {                         \
    bv[n][0] = *(const short8*)(base + bO[n] +                            \
                                (((((S0) << 1) + lg2) ^ bX[n]) << 4));    \
    bv[n][1] = *(const short8*)(base + bO[n] +                            \
                                (((((S1) << 1) + lg2) ^ bX[n]) << 4));    \
  }
#define MFMA8()                                                           \
  __builtin_amdgcn_s_setprio(1);                                          \
  _Pragma("unroll") for (int s = 0; s < 2; ++s)                           \
  _Pragma("unroll") for (int m = 0; m < 2; ++m)                           \
  _Pragma("unroll") for (int n = 0; n < 2; ++n)                           \
    acc[m][n] = __builtin_amdgcn_mfma_f32_32x32x16_bf16(                  \
        av[m][s], bv[n][s], acc[m][n], 0, 0, 0);                          \
  __builtin_amdgcn_s_setprio(0);

  f32x16 acc[2][2];
#pragma unroll
  for (int m = 0; m < 2; ++m)
#pragma unroll
    for (int n = 0; n < 2; ++n)
#pragma unroll
      for (int r = 0; r < 16; ++r) acc[m][n][r] = 0.f;

  const int NT = K >> 6;    // K-tiles of 64

  short8 av[2][2], bv[2][2];

  // ---- prologue: stage tile 0
  STG(0);

  for (int t = 0; t < NT; ++t) {
    const char* base = smem + ((t & 1) << 16);

    VMC0();                 // own STG(t) landed (issued one full tile ago)
    BARRIER();              // all waves' STG(t) landed; all done reading slot t^1
    if (t + 1 < NT) STG(t + 1);

    // slices 0,1
    RD2(0, 1);
    LGKM0();
    SCHED0();
    MFMA8();
    SCHED0();

    // slices 2,3 (reuse frag regs; in-order WAR safe)
    RD2(2, 3);
    LGKM0();
    SCHED0();
    MFMA8();
    SCHED0();
  }
#undef STG
#undef RD2
#undef MFMA8

  // ---- epilogue (C/D: col = lane&31, row = (r&3) + 8*(r>>2) + 4*(lane>>5))
  float bvv[2];
  if (MODE == 0 || MODE == 1) {
    const float* bias = biasAll + (size_t)z * biasBatch;
#pragma unroll
    for (int n = 0; n < 2; ++n) bvv[n] = bias[bn + wc * 64 + n * 32 + la31];
  }
#pragma unroll
  for (int m = 0; m < 2; ++m)
#pragma unroll
    for (int n = 0; n < 2; ++n)
#pragma unroll
      for (int r = 0; r < 16; ++r) {
        const int grow = bm + wr * 64 + m * 32 + (r & 3) + 8 * (r >> 2) + 4 * lg2;
        const int gcol = bn + wc * 64 + n * 32 + la31;
        float val = acc[m][n][r];
        if (MODE == 0 || MODE == 1) val += bvv[n];
        if (MODE == 2) val *= scale;
        if (MODE == 0 || MODE == 2) {
          unsigned short* o = (unsigned short*)outAll + (size_t)z * outBatch;
          o[(size_t)grow * ldOut + gcol] = f2bf(val);
        } else if (MODE == 1) {
          unsigned short* o = (unsigned short*)outAll + (size_t)z * outBatch;
          o[(size_t)gcol * ldOut + grow] = f2bf(val);
        } else {
          float* o = (float*)outAll + (size_t)z * outBatch;
          o[(size_t)grow * ldOut + gcol] = val;
        }
      }
}

// ---------------- row softmax, in place on bf16 [nrows][SEQ] ----------------
__global__ __launch_bounds__(256) void softmax_kernel(unsigned short* __restrict__ Sb) {
  const size_t row = blockIdx.x;
  unsigned short* p = Sb + row * (size_t)SEQ;
  const int tid = threadIdx.x;
  const int lane = tid & 63, wid = tid >> 6;
  float v[16];
  const short8 u0 = *(const short8*)&p[tid * 16];
  const short8 u1 = *(const short8*)&p[tid * 16 + 8];
#pragma unroll
  for (int j = 0; j < 8; ++j) v[j] = bf2f((unsigned short)u0[j]);
#pragma unroll
  for (int j = 0; j < 8; ++j) v[8 + j] = bf2f((unsigned short)u1[j]);
  float mx = v[0];
#pragma unroll
  for (int j = 1; j < 16; ++j) mx = fmaxf(mx, v[j]);
#pragma unroll
  for (int off = 32; off; off >>= 1) mx = fmaxf(mx, __shfl_xor(mx, off));
  __shared__ float red[8];
  if (lane == 0) red[wid] = mx;
  __syncthreads();
  mx = fmaxf(fmaxf(red[0], red[1]), fmaxf(red[2], red[3]));
  float s = 0.f;
#pragma unroll
  for (int j = 0; j < 16; ++j) { v[j] = __expf(v[j] - mx); s += v[j]; }
#pragma unroll
  for (int off = 32; off; off >>= 1) s += __shfl_xor(s, off);
  if (lane == 0) red[4 + wid] = s;
  __syncthreads();
  s = (red[4] + red[5]) + (red[6] + red[7]);
  const float inv = 1.0f / s;
  short8 o0, o1;
#pragma unroll
  for (int j = 0; j < 8; ++j) o0[j] = (short)f2bf(v[j] * inv);
#pragma unroll
  for (int j = 0; j < 8; ++j) o1[j] = (short)f2bf(v[8 + j] * inv);
  *(short8*)&p[tid * 16] = o0;
  *(short8*)&p[tid * 16 + 8] = o1;
}

extern "C" void kernel_launch(void* const* d_in, const int* in_sizes, int n_in,
                              void* d_out, int out_size, void* d_ws, size_t ws_size,
                              hipStream_t stream) {
  const float* h  = (const float*)d_in[0];
  const float* Wq = (const float*)d_in[1];
  const float* bq = (const float*)d_in[2];
  const float* Wk = (const float*)d_in[3];
  const float* bk = (const float*)d_in[4];
  const float* Wv = (const float*)d_in[5];
  const float* bv = (const float*)d_in[6];
  float* out = (float*)d_out;
  char* ws = (char*)d_ws;

  // allow 128KB dynamic LDS for the GEMM kernels (idempotent, not a stream op)
  (void)hipFuncSetAttribute((const void*)&gemm1024_kernel<0>,
                            hipFuncAttributeMaxDynamicSharedMemorySize, 131072);
  (void)hipFuncSetAttribute((const void*)&gemm1024_kernel<1>,
                            hipFuncAttributeMaxDynamicSharedMemorySize, 131072);
  (void)hipFuncSetAttribute((const void*)&gemm1024_kernel<2>,
                            hipFuncAttributeMaxDynamicSharedMemorySize, 131072);
  (void)hipFuncSetAttribute((const void*)&gemm1024_kernel<3>,
                            hipFuncAttributeMaxDynamicSharedMemorySize, 131072);

  // ws layout (224 MB):
  //  [0,32MB)    h_bf16 [S][HID]          -- dead after projections
  //  [32,128MB)  Wt bf16 [12][E][HID]     -- dead after projections
  //  [0,128MB)   Sb bf16 [H][S][S]        -- scores/probs (reuses the two above)
  //  [128,160)   Qb bf16 [H][S][E]
  //  [160,192)   Kb bf16 [H][S][E]
  //  [192,224)   Vt bf16 [H][E][S]
  unsigned short* hB = (unsigned short*)ws;
  unsigned short* wt = (unsigned short*)(ws + (32ull << 20));
  unsigned short* Sb = (unsigned short*)ws;
  unsigned short* Qb = (unsigned short*)(ws + (128ull << 20));
  unsigned short* Kb = (unsigned short*)(ws + (160ull << 20));
  unsigned short* Vt = (unsigned short*)(ws + (192ull << 20));

  const long long WED = (long long)EDIM * HID;   // per-(mat,head) Wt elems
  const long long QKB = (long long)SEQ * EDIM;   // per-head Q/K elems
  const long long SSB = (long long)SEQ * SEQ;    // per-head score elems

  hconv_kernel<<<dim3((SEQ * (size_t)HID) / (256 * 8)), 256, 0, stream>>>(h, hB);
  wconv_kernel<<<dim3((HID / 64) * (EDIM / 64), 12), 256, 0, stream>>>(Wq, Wk, Wv, wt);

  // Projections: M=S=4096, N=E=1024, K=HID  -> grid (4 x 16 x 4) = 256 blocks, 1-D
  gemm1024_kernel<0><<<dim3(4 * 16 * 4), 1024, 131072, stream>>>(
      hB, wt + 0 * WED, 0, WED, HID, bq, EDIM, Qb, QKB, EDIM, 1.f, 4, 64);
  gemm1024_kernel<0><<<dim3(4 * 16 * 4), 1024, 131072, stream>>>(
      hB, wt + 4 * WED, 0, WED, HID, bk, EDIM, Kb, QKB, EDIM, 1.f, 4, 64);
  gemm1024_kernel<1><<<dim3(4 * 16 * 4), 1024, 131072, stream>>>(
      hB, wt + 8 * WED, 0, WED, HID, bv, EDIM, Vt, QKB, SEQ, 1.f, 4, 64);

  // Scores: S = Q K^T / 32   (M=N=S, K=E) -> grid (16 x 16 x 4) = 1024 blocks
  gemm1024_kernel<2><<<dim3(16 * 16 * 4), 1024, 131072, stream>>>(
      Qb, Kb, QKB, QKB, EDIM, nullptr, 0, Sb, SSB, SEQ, 0.03125f, 16, 256);

  // Softmax over rows, in place
  softmax_kernel<<<dim3(NHEAD * SEQ), 256, 0, stream>>>(Sb);

  // Out: O = P V  (M=S, N=E, K=S), written to out[s][head*E + e] as f32
  gemm1024_kernel<3><<<dim3(4 * 16 * 4), 1024, 131072, stream>>>(
      Sb, Vt, SSB, QKB, SEQ, nullptr, 0, out, (long long)EDIM, NHEAD * EDIM, 1.f, 4, 64);
}

// Round 11
// 886.712 us; speedup vs baseline: 1.1158x; 1.0132x over previous
//
#include <hip/hip_runtime.h>

#define SEQ   4096
#define HID   4096
#define EDIM  1024
#define NHEAD 4

typedef __attribute__((ext_vector_type(8))) short short8;
typedef __attribute__((ext_vector_type(16))) float f32x16;

typedef const __attribute__((address_space(1))) void* gas_ptr;
typedef __attribute__((address_space(3))) void* las_ptr;
#define GLD16(g, l) __builtin_amdgcn_global_load_lds((gas_ptr)(g), (las_ptr)(l), 16, 0, 0)

#define BARRIER() __builtin_amdgcn_s_barrier()
#define SCHED0()  __builtin_amdgcn_sched_barrier(0)
#define LGKM0()   asm volatile("s_waitcnt lgkmcnt(0)" ::: "memory")
#define VMC0()    asm volatile("s_waitcnt vmcnt(0)" ::: "memory")

__device__ __forceinline__ unsigned short f2bf(float f) {
  union { float f; unsigned u; } v; v.f = f;
  unsigned r = v.u + 0x7fffu + ((v.u >> 16) & 1u);  // RNE
  return (unsigned short)(r >> 16);
}
__device__ __forceinline__ float bf2f(unsigned short u) {
  union { unsigned u; float f; } v; v.u = ((unsigned)u) << 16;
  return v.f;
}

// ---------------- h: f32 -> bf16 ----------------
__global__ __launch_bounds__(256) void hconv_kernel(const float* __restrict__ in,
                                                    unsigned short* __restrict__ out) {
  size_t i = ((size_t)blockIdx.x * 256 + threadIdx.x) * 8;
  const float4 a = *(const float4*)(in + i);
  const float4 b = *(const float4*)(in + i + 4);
  short8 o;
  o[0] = (short)f2bf(a.x); o[1] = (short)f2bf(a.y);
  o[2] = (short)f2bf(a.z); o[3] = (short)f2bf(a.w);
  o[4] = (short)f2bf(b.x); o[5] = (short)f2bf(b.y);
  o[6] = (short)f2bf(b.z); o[7] = (short)f2bf(b.w);
  *(short8*)(out + i) = o;
}

// ---------------- W [mat][head][D][E] f32 -> Wt [mat*4+head][E][D] bf16 ----------------
__global__ __launch_bounds__(256) void wconv_kernel(const float* __restrict__ Wq,
                                                    const float* __restrict__ Wk,
                                                    const float* __restrict__ Wv,
                                                    unsigned short* __restrict__ wt) {
  const int mh = blockIdx.y;               // 0..11
  const int mat = mh >> 2, head = mh & 3;
  const float* W = (mat == 0 ? Wq : (mat == 1 ? Wk : Wv)) + (size_t)head * HID * EDIM; // [D][E]
  unsigned short* out = wt + (size_t)mh * EDIM * HID;                                  // [E][D]
  const int tile = blockIdx.x;             // (D/64)*(E/64) = 64*16
  const int td = tile >> 4;                // d-tile 0..63
  const int te = tile & 15;                // e-tile 0..15
  __shared__ float lds[64][65];
  const int tid = threadIdx.x;
  const int r = tid >> 4, c4 = (tid & 15) * 4;
#pragma unroll
  for (int it = 0; it < 4; ++it) {
    int dr = r + 16 * it;
    const float4 v = *(const float4*)&W[(size_t)(td * 64 + dr) * EDIM + te * 64 + c4];
    lds[dr][c4 + 0] = v.x; lds[dr][c4 + 1] = v.y;
    lds[dr][c4 + 2] = v.z; lds[dr][c4 + 3] = v.w;
  }
  __syncthreads();
#pragma unroll
  for (int it = 0; it < 4; ++it) {
    int er = r + 16 * it;
    ushort4 o;
    o.x = f2bf(lds[c4 + 0][er]); o.y = f2bf(lds[c4 + 1][er]);
    o.z = f2bf(lds[c4 + 2][er]); o.w = f2bf(lds[c4 + 3][er]);
    *(ushort4*)&out[(size_t)(te * 64 + er) * HID + td * 64 + c4] = o;
  }
}

// ---------------- 128x128 bf16 MFMA GEMM (32x32x16), 2 blocks/CU overlap ----------------
// C = A * Bt^T. A [M][K] row-major, Bt [N][K] row-major. BK=64. 256 threads = 4 waves
// (2Mx2N), wave tile 64x64 = 2x2 tiles of 32x32 -> acc f32x16[2][2] = 64 VGPR, total
// ~140 -> __launch_bounds__(256,2). LDS = 2 slots x 32KB = 64KB -> TWO independent
// blocks/CU (m97/m114 mechanism: cross-BLOCK overlap hides each block's vmcnt/barrier/
// LDS bursts in the other block's MFMAs -- the lever every 128KB/1-block design lacked).
// Per-block loop = r6-proven minimal: one VMC0 + one BARRIER per K-tile; STG(t+1) into
// slot t^1 (all reads this iter hit slot t&1; LGKM0 before iter end -> WAR safe).
// Swizzle (r5/r8-verified, 0 conflicts): phys 16B-slot = logical ^ f(row),
// f(row)=(row^(row>>3))&7; staging source pre-permuted (row=j*32+srow -> f ^= (j&1)*4).
// Frag maps: A/B lane l: row/col = l&31, k = (l>>5)*8 + j.
// C/D (verified m74/m101): col = lane&31, row = (r&3) + 8*(r>>2) + 4*(lane>>5).
// MODE 0: bf16 out [row][col], +bias[col]
// MODE 1: bf16 out [col][row], +bias[col]   (transposed write, for V^T)
// MODE 2: bf16 out [row][col], *scale       (scores)
// MODE 3: f32  out [row][col]               (final output)
template <int MODE>
__global__ __launch_bounds__(256, 2) void gemm128d_kernel(
    const unsigned short* __restrict__ Aall, const unsigned short* __restrict__ Ball,
    long long aBatch, long long bBatch, int K,
    const float* __restrict__ biasAll, long long biasBatch,
    void* __restrict__ outAll, long long outBatch, int ldOut, float scale,
    int gx, int gxy) {
  extern __shared__ char smem[];

  // XCD-aware bijective block swizzle (all grids have nwg % 8 == 0)
  const int nwg = (int)gridDim.x;
  const int lin = (int)blockIdx.x;
  int wg = (lin & 7) * (nwg >> 3) + (lin >> 3);
  const int z = wg / gxy; wg -= z * gxy;
  const int by = wg / gx;
  const int bx = wg - by * gx;
  const int bm = by * 128, bn = bx * 128;

  const unsigned short* A = Aall + (size_t)z * aBatch;
  const unsigned short* B = Ball + (size_t)z * bBatch;

  const int tid = threadIdx.x;           // 0..255
  const int lane = tid & 63, wid = tid >> 6;   // 4 waves
  const int wr = wid >> 1, wc = wid & 1;       // 2 x 2 wave grid
  const int la31 = lane & 31, lg2 = lane >> 5;

  // ---- staging: per matrix 128 rows x 128B (16KB); thread covers chunks j*256+tid,
  // j=0..3 -> row = j*32 + (tid>>3), phys slot = tid&7. Source k pre-permuted:
  // f(row) = (row ^ (row>>3)) & 7 = f(srow) ^ (j&1)*4.
  const int srow = tid >> 3;                                // 0..31
  const int skE = (((tid & 7) ^ ((srow ^ (srow >> 3)) & 7))) * 8;
  const int skO = skE ^ 32;
  const unsigned short* aS0 = A + (size_t)(bm +  0 + srow) * K + skE;
  const unsigned short* aS1 = A + (size_t)(bm + 32 + srow) * K + skO;
  const unsigned short* aS2 = A + (size_t)(bm + 64 + srow) * K + skE;
  const unsigned short* aS3 = A + (size_t)(bm + 96 + srow) * K + skO;
  const unsigned short* bS0 = B + (size_t)(bn +  0 + srow) * K + skE;
  const unsigned short* bS1 = B + (size_t)(bn + 32 + srow) * K + skO;
  const unsigned short* bS2 = B + (size_t)(bn + 64 + srow) * K + skE;
  const unsigned short* bS3 = B + (size_t)(bn + 96 + srow) * K + skO;

// slot = 32KB: A 16KB @0, B 16KB @16384
#define STG(tt)                                                           \
  do {                                                                    \
    char* _d = smem + (((tt) & 1) << 15) + tid * 16;                      \
    GLD16(aS0 + (size_t)(tt) * 64, _d);                                   \
    GLD16(aS1 + (size_t)(tt) * 64, _d + 4096);                            \
    GLD16(aS2 + (size_t)(tt) * 64, _d + 8192);                            \
    GLD16(aS3 + (size_t)(tt) * 64, _d + 12288);                          \
    GLD16(bS0 + (size_t)(tt) * 64, _d + 16384);                          \
    GLD16(bS1 + (size_t)(tt) * 64, _d + 20480);                          \
    GLD16(bS2 + (size_t)(tt) * 64, _d + 24576);                          \
    GLD16(bS3 + (size_t)(tt) * 64, _d + 28672);                          \
  } while (0)

  // ---- fragment read bases (row stride 128B, XOR-swizzled 16B slots)
  int aO[2], aX[2];
#pragma unroll
  for (int m = 0; m < 2; ++m) {
    const int arow = wr * 64 + m * 32 + la31;
    aO[m] = arow * 128;
    aX[m] = (arow ^ (arow >> 3)) & 7;
  }
  int bO[2], bX[2];
#pragma unroll
  for (int n = 0; n < 2; ++n) {
    const int brow = wc * 64 + n * 32 + la31;
    bO[n] = 16384 + brow * 128;
    bX[n] = (brow ^ (brow >> 3)) & 7;
  }

#define RD2(S0, S1)                                                       \
  _Pragma("unroll") for (int m = 0; m < 2; ++m) {                         \
    av[m][0] = *(const short8*)(base + aO[m] +                            \
                                (((((S0) << 1) + lg2) ^ aX[m]) << 4));    \
    av[m][1] = *(const short8*)(base + aO[m] +                            \
                                (((((S1) << 1) + lg2) ^ aX[m]) << 4));    \
  }                                                                       \
  _Pragma("unroll") for (int n = 0; n < 2; ++n) {                         \
    bv[n][0] = *(const short8*)(base + bO[n] +                            \
                                (((((S0) << 1) + lg2) ^ bX[n]) << 4));    \
    bv[n][1] = *(const short8*)(base + bO[n] +                            \
                                (((((S1) << 1) + lg2) ^ bX[n]) << 4));    \
  }
#define MFMA8()                                                           \
  __builtin_amdgcn_s_setprio(1);                                          \
  _Pragma("unroll") for (int s = 0; s < 2; ++s)                           \
  _Pragma("unroll") for (int m = 0; m < 2; ++m)                           \
  _Pragma("unroll") for (int n = 0; n < 2; ++n)                           \
    acc[m][n] = __builtin_amdgcn_mfma_f32_32x32x16_bf16(                  \
        av[m][s], bv[n][s], acc[m][n], 0, 0, 0);                          \
  __builtin_amdgcn_s_setprio(0);

  f32x16 acc[2][2];
#pragma unroll
  for (int m = 0; m < 2; ++m)
#pragma unroll
    for (int n = 0; n < 2; ++n)
#pragma unroll
      for (int r = 0; r < 16; ++r) acc[m][n][r] = 0.f;

  const int NT = K >> 6;    // K-tiles of 64

  short8 av[2][2], bv[2][2];

  // ---- prologue: stage tile 0
  STG(0);

  for (int t = 0; t < NT; ++t) {
    const char* base = smem + ((t & 1) << 15);

    VMC0();                 // own STG(t) landed (issued one full tile ago)
    BARRIER();              // all waves' STG(t) landed; all done reading slot t^1
    if (t + 1 < NT) STG(t + 1);

    // slices 0,1
    RD2(0, 1);
    LGKM0();
    SCHED0();
    MFMA8();
    SCHED0();

    // slices 2,3 (reuse frag regs; in-order WAR safe)
    RD2(2, 3);
    LGKM0();
    SCHED0();
    MFMA8();
    SCHED0();
  }
#undef STG
#undef RD2
#undef MFMA8

  // ---- epilogue (C/D: col = lane&31, row = (r&3) + 8*(r>>2) + 4*(lane>>5))
  float bvv[2];
  if (MODE == 0 || MODE == 1) {
    const float* bias = biasAll + (size_t)z * biasBatch;
#pragma unroll
    for (int n = 0; n < 2; ++n) bvv[n] = bias[bn + wc * 64 + n * 32 + la31];
  }
#pragma unroll
  for (int m = 0; m < 2; ++m)
#pragma unroll
    for (int n = 0; n < 2; ++n)
#pragma unroll
      for (int r = 0; r < 16; ++r) {
        const int grow = bm + wr * 64 + m * 32 + (r & 3) + 8 * (r >> 2) + 4 * lg2;
        const int gcol = bn + wc * 64 + n * 32 + la31;
        float val = acc[m][n][r];
        if (MODE == 0 || MODE == 1) val += bvv[n];
        if (MODE == 2) val *= scale;
        if (MODE == 0 || MODE == 2) {
          unsigned short* o = (unsigned short*)outAll + (size_t)z * outBatch;
          o[(size_t)grow * ldOut + gcol] = f2bf(val);
        } else if (MODE == 1) {
          unsigned short* o = (unsigned short*)outAll + (size_t)z * outBatch;
          o[(size_t)gcol * ldOut + grow] = f2bf(val);
        } else {
          float* o = (float*)outAll + (size_t)z * outBatch;
          o[(size_t)grow * ldOut + gcol] = val;
        }
      }
}

// ---------------- row softmax, in place on bf16 [nrows][SEQ] ----------------
__global__ __launch_bounds__(256) void softmax_kernel(unsigned short* __restrict__ Sb) {
  const size_t row = blockIdx.x;
  unsigned short* p = Sb + row * (size_t)SEQ;
  const int tid = threadIdx.x;
  const int lane = tid & 63, wid = tid >> 6;
  float v[16];
  const short8 u0 = *(const short8*)&p[tid * 16];
  const short8 u1 = *(const short8*)&p[tid * 16 + 8];
#pragma unroll
  for (int j = 0; j < 8; ++j) v[j] = bf2f((unsigned short)u0[j]);
#pragma unroll
  for (int j = 0; j < 8; ++j) v[8 + j] = bf2f((unsigned short)u1[j]);
  float mx = v[0];
#pragma unroll
  for (int j = 1; j < 16; ++j) mx = fmaxf(mx, v[j]);
#pragma unroll
  for (int off = 32; off; off >>= 1) mx = fmaxf(mx, __shfl_xor(mx, off));
  __shared__ float red[8];
  if (lane == 0) red[wid] = mx;
  __syncthreads();
  mx = fmaxf(fmaxf(red[0], red[1]), fmaxf(red[2], red[3]));
  float s = 0.f;
#pragma unroll
  for (int j = 0; j < 16; ++j) { v[j] = __expf(v[j] - mx); s += v[j]; }
#pragma unroll
  for (int off = 32; off; off >>= 1) s += __shfl_xor(s, off);
  if (lane == 0) red[4 + wid] = s;
  __syncthreads();
  s = (red[4] + red[5]) + (red[6] + red[7]);
  const float inv = 1.0f / s;
  short8 o0, o1;
#pragma unroll
  for (int j = 0; j < 8; ++j) o0[j] = (short)f2bf(v[j] * inv);
#pragma unroll
  for (int j = 0; j < 8; ++j) o1[j] = (short)f2bf(v[8 + j] * inv);
  *(short8*)&p[tid * 16] = o0;
  *(short8*)&p[tid * 16 + 8] = o1;
}

extern "C" void kernel_launch(void* const* d_in, const int* in_sizes, int n_in,
                              void* d_out, int out_size, void* d_ws, size_t ws_size,
                              hipStream_t stream) {
  const float* h  = (const float*)d_in[0];
  const float* Wq = (const float*)d_in[1];
  const float* bq = (const float*)d_in[2];
  const float* Wk = (const float*)d_in[3];
  const float* bk = (const float*)d_in[4];
  const float* Wv = (const float*)d_in[5];
  const float* bv = (const float*)d_in[6];
  float* out = (float*)d_out;
  char* ws = (char*)d_ws;

  (void)hipFuncSetAttribute((const void*)&gemm128d_kernel<0>,
                            hipFuncAttributeMaxDynamicSharedMemorySize, 65536);
  (void)hipFuncSetAttribute((const void*)&gemm128d_kernel<1>,
                            hipFuncAttributeMaxDynamicSharedMemorySize, 65536);
  (void)hipFuncSetAttribute((const void*)&gemm128d_kernel<2>,
                            hipFuncAttributeMaxDynamicSharedMemorySize, 65536);
  (void)hipFuncSetAttribute((const void*)&gemm128d_kernel<3>,
                            hipFuncAttributeMaxDynamicSharedMemorySize, 65536);

  // ws layout (224 MB):
  //  [0,32MB)    h_bf16 [S][HID]          -- dead after projections
  //  [32,128MB)  Wt bf16 [12][E][HID]     -- dead after projections
  //  [0,128MB)   Sb bf16 [H][S][S]        -- scores/probs (reuses the two above)
  //  [128,160)   Qb bf16 [H][S][E]
  //  [160,192)   Kb bf16 [H][S][E]
  //  [192,224)   Vt bf16 [H][E][S]
  unsigned short* hB = (unsigned short*)ws;
  unsigned short* wt = (unsigned short*)(ws + (32ull << 20));
  unsigned short* Sb = (unsigned short*)ws;
  unsigned short* Qb = (unsigned short*)(ws + (128ull << 20));
  unsigned short* Kb = (unsigned short*)(ws + (160ull << 20));
  unsigned short* Vt = (unsigned short*)(ws + (192ull << 20));

  const long long WED = (long long)EDIM * HID;   // per-(mat,head) Wt elems
  const long long QKB = (long long)SEQ * EDIM;   // per-head Q/K elems
  const long long SSB = (long long)SEQ * SEQ;    // per-head score elems

  hconv_kernel<<<dim3((SEQ * (size_t)HID) / (256 * 8)), 256, 0, stream>>>(h, hB);
  wconv_kernel<<<dim3((HID / 64) * (EDIM / 64), 12), 256, 0, stream>>>(Wq, Wk, Wv, wt);

  // Projections: M=S=4096, N=E=1024, K=HID  -> grid (8 x 32 x 4) = 1024 blocks
  gemm128d_kernel<0><<<dim3(8 * 32 * 4), 256, 65536, stream>>>(
      hB, wt + 0 * WED, 0, WED, HID, bq, EDIM, Qb, QKB, EDIM, 1.f, 8, 256);
  gemm128d_kernel<0><<<dim3(8 * 32 * 4), 256, 65536, stream>>>(
      hB, wt + 4 * WED, 0, WED, HID, bk, EDIM, Kb, QKB, EDIM, 1.f, 8, 256);
  gemm128d_kernel<1><<<dim3(8 * 32 * 4), 256, 65536, stream>>>(
      hB, wt + 8 * WED, 0, WED, HID, bv, EDIM, Vt, QKB, SEQ, 1.f, 8, 256);

  // Scores: S = Q K^T / 32   (M=N=S, K=E) -> grid (32 x 32 x 4) = 4096 blocks
  gemm128d_kernel<2><<<dim3(32 * 32 * 4), 256, 65536, stream>>>(
      Qb, Kb, QKB, QKB, EDIM, nullptr, 0, Sb, SSB, SEQ, 0.03125f, 32, 1024);

  // Softmax over rows, in place
  softmax_kernel<<<dim3(NHEAD * SEQ), 256, 0, stream>>>(Sb);

  // Out: O = P V  (M=S, N=E, K=S), written to out[s][head*E + e] as f32
  gemm128d_kernel<3><<<dim3(8 * 32 * 4), 256, 65536, stream>>>(
      Sb, Vt, SSB, QKB, SEQ, nullptr, 0, out, (long long)EDIM, NHEAD * EDIM, 1.f, 8, 256);
}